// Round 8
// baseline (88.580 us; speedup 1.0000x reference)
//
#include <hip/hip_runtime.h>
#include <hip/hip_bf16.h>
#include <stdint.h>

typedef __attribute__((ext_vector_type(8))) short short8;
typedef __attribute__((ext_vector_type(4))) float f32x4;

#define B_   16
#define C_   64
#define H_   112
#define W_   112
#define O_   128
#define HP   114
#define HWP  (HP*HP)          // 12996 padded plane positions
#define HW   (H_*W_)          // 12544
#define NROWS 362             // staged A-union rows (exact bound)

__device__ __forceinline__ unsigned short f2bf(float f) {
    union { float f; uint32_t u; } v; v.f = f;
    uint32_t u = v.u;
    u += 0x7fffu + ((u >> 16) & 1u);   // round-to-nearest-even
    return (unsigned short)(u >> 16);
}

// ---------------- Pass 0: weight (c,kh,kw,o) f32 -> fragment-ordered bf16 ----------
// Layout [s][ks][wc][nf][lane][j]: each wave's MFMA B-fragment load is one
// perfectly coalesced 1KB global_load_dwordx4 from L2-resident wbuf.
__global__ void wtrans(const float* __restrict__ wt, unsigned short* __restrict__ wbuf)
{
    int f = blockIdx.x * 256 + threadIdx.x;        // [0, 73728)
    int j    = f & 7;
    int lane = (f >> 3) & 63;
    int nf   = (f >> 9) & 3;
    int wc   = (f >> 11) & 1;
    int ks   = (f >> 12) & 1;
    int s    = f >> 13;
    int o = wc * 64 + nf * 16 + (lane & 15);
    int c = (ks * 4 + (lane >> 4)) * 8 + j;
    int kh = s / 3, kw = s % 3;
    wbuf[f] = f2bf(wt[(((size_t)c * 3 + kh) * 3 + kw) * O_ + o]);
}

// ---------------- Pass 1: FULLY-FUSED implicit-GEMM conv ----------------
// No xpad intermediate: each block gathers its 362-row A-union straight from
// x (NCHW f32), converts to bf16 in-register, ds_write_b128 into the
// XOR-swizzled LDS layout. One barrier, 288 MFMA/wave barrier-free, B from L2.
__global__ __launch_bounds__(256, 2) void conv_gemm(
    const float* __restrict__ x,
    const char* __restrict__ wbuf,
    float* __restrict__ out)
{
    __shared__ char ldsA[NROWS * 128];   // 46336 B; 2 blocks/CU = 92.7 KB

    const int t = threadIdx.x;
    const int lane = t & 63, wid = t >> 6;
    const int wr = wid >> 1, wc = wid & 1;
    const int bid0 = blockIdx.x;
    const int bid = (bid0 & 7) * 196 + (bid0 >> 3);  // XCD swizzle, 1568 = 8*196 exact
    const int b = bid / 98;                 // 98 M-tiles per batch, exact
    const int ml0 = (bid % 98) * 128;
    const int oh0 = ml0 / W_;
    const int pbase = ml0 + 2 * oh0;        // first padded-plane row of the union

    // ---- Staging: 362 rows x 8 channel-octets = 2896 units, 16B each.
    // Unit idx -> LDS byte idx*16 (linear, dense: conflict-free b128 writes).
    // Data: channel-octet (pos ^ (r&7)) of padded row pbase+r -> the same
    // XOR-swizzled layout the MFMA reader uses. Borders: zero-fill predicate.
    const float* xb = x + (size_t)b * C_ * HW;
    #pragma unroll 4
    for (int i = 0; i < 12; ++i) {
        const int idx = i * 256 + t;
        if (i < 11 || idx < 2896) {
            const int r = idx >> 3, pos = idx & 7;
            const int p = pbase + r;
            const int ph = p / HP, pw = p - ph * HP;
            union { uint32_t u[4]; short8 s; } v;
            v.u[0] = v.u[1] = v.u[2] = v.u[3] = 0;
            if (ph >= 1 && ph <= 112 && pw >= 1 && pw <= 112) {
                const float* src = xb + (size_t)((pos ^ (r & 7)) * 8) * HW
                                 + (ph - 1) * W_ + (pw - 1);
                float f0 = src[0],      f1 = src[HW],     f2 = src[2*HW], f3 = src[3*HW];
                float f4 = src[4*HW],   f5 = src[5*HW],   f6 = src[6*HW], f7 = src[7*HW];
                asm("v_cvt_pk_bf16_f32 %0, %1, %2" : "=v"(v.u[0]) : "v"(f0), "v"(f1));
                asm("v_cvt_pk_bf16_f32 %0, %1, %2" : "=v"(v.u[1]) : "v"(f2), "v"(f3));
                asm("v_cvt_pk_bf16_f32 %0, %1, %2" : "=v"(v.u[2]) : "v"(f4), "v"(f5));
                asm("v_cvt_pk_bf16_f32 %0, %1, %2" : "=v"(v.u[3]) : "v"(f6), "v"(f7));
            }
            *(short8*)(ldsA + (size_t)idx * 16) = v.s;
        }
    }
    __syncthreads();   // single barrier: all MFMA data in LDS

    // Per-fragment LDS base rows (per-lane): row = ml + 2*oh - pbase
    int rowb[4];
    #pragma unroll
    for (int mf = 0; mf < 4; ++mf) {
        int ml = ml0 + wr * 64 + mf * 16 + (lane & 15);
        int oh = ml / W_;
        rowb[mf] = ml + 2 * oh - pbase;
    }
    const int kq = lane >> 4;   // k-quarter 0..3

    f32x4 acc[4][4] = {};

    #pragma unroll
    for (int s = 0; s < 9; ++s) {
        const int soff = (s / 3) * HP + (s % 3);
        const char* wb = wbuf + s * 16384 + wc * 4096 + lane * 16;

        #pragma unroll
        for (int ks = 0; ks < 2; ++ks) {
            // B fragments: 4 coalesced 1KB loads per wave from L2-resident wbuf
            short8 bv[4];
            #pragma unroll
            for (int nf = 0; nf < 4; ++nf)
                bv[nf] = *(const short8*)(wb + ks * 8192 + nf * 1024);

            short8 av[4];
            #pragma unroll
            for (int mf = 0; mf < 4; ++mf) {
                const int lrow = rowb[mf] + soff;
                const int ck = (ks * 4 + kq) ^ (lrow & 7);
                av[mf] = *(const short8*)(ldsA + lrow * 128 + (ck << 4));
            }
            __builtin_amdgcn_s_setprio(1);
            #pragma unroll
            for (int mf = 0; mf < 4; ++mf)
                #pragma unroll
                for (int nf = 0; nf < 4; ++nf)
                    acc[mf][nf] = __builtin_amdgcn_mfma_f32_16x16x32_bf16(
                        av[mf], bv[nf], acc[mf][nf], 0, 0, 0);
            __builtin_amdgcn_s_setprio(0);
        }
    }

    // Epilogue: C/D layout col=lane&15 (o), row=(lane>>4)*4+reg (m).
    // Normal stores (L2 merges the 4-lane 16B fragments into full 64B lines).
    const int oc = wc * 64 + (lane & 15);
    const int mrow = ml0 + wr * 64 + ((lane >> 4) << 2);
    #pragma unroll
    for (int mf = 0; mf < 4; ++mf) {
        #pragma unroll
        for (int nf = 0; nf < 4; ++nf) {
            float* dst = out + ((size_t)(b * O_ + oc + nf * 16) * HW) + mrow + mf * 16;
            *(f32x4*)dst = acc[mf][nf];
        }
    }
}

extern "C" void kernel_launch(void* const* d_in, const int* in_sizes, int n_in,
                              void* d_out, int out_size, void* d_ws, size_t ws_size,
                              hipStream_t stream) {
    const float* x  = (const float*)d_in[0];
    const float* wt = (const float*)d_in[1];
    float* out = (float*)d_out;
    char* wbuf = (char*)d_ws;

    hipLaunchKernelGGL(wtrans, dim3(288), dim3(256), 0, stream,
                       wt, (unsigned short*)wbuf);
    hipLaunchKernelGGL(conv_gemm, dim3(1568), dim3(256), 0, stream,
                       x, wbuf, out);
}

// Round 9
// 71.938 us; speedup vs baseline: 1.2313x; 1.2313x over previous
//
#include <hip/hip_runtime.h>
#include <hip/hip_bf16.h>
#include <stdint.h>

typedef __attribute__((ext_vector_type(8))) short short8;
typedef __attribute__((ext_vector_type(4))) float f32x4;

#define B_   16
#define C_   64
#define H_   112
#define W_   112
#define O_   128
#define HP   114
#define HW   (H_*W_)          // 12544
#define NROWS 362             // staged A-union rows (exact bound)

__device__ __forceinline__ unsigned short f2bf(float f) {
    union { float f; uint32_t u; } v; v.f = f;
    uint32_t u = v.u;
    u += 0x7fffu + ((u >> 16) & 1u);   // round-to-nearest-even
    return (unsigned short)(u >> 16);
}

// ---------------- Pass 0: weight (c,kh,kw,o) f32 -> fragment-ordered bf16 ----------
// Layout [s][ks][wc][nf][lane][j]: each wave's MFMA B-fragment load is one
// perfectly coalesced 1KB global_load_dwordx4 from L2-resident wbuf.
__global__ void wtrans(const float* __restrict__ wt, unsigned short* __restrict__ wbuf)
{
    int f = blockIdx.x * 256 + threadIdx.x;        // [0, 73728)
    int j    = f & 7;
    int lane = (f >> 3) & 63;
    int nf   = (f >> 9) & 3;
    int wc   = (f >> 11) & 1;
    int ks   = (f >> 12) & 1;
    int s    = f >> 13;
    int o = wc * 64 + nf * 16 + (lane & 15);
    int c = (ks * 4 + (lane >> 4)) * 8 + j;
    int kh = s / 3, kw = s % 3;
    wbuf[f] = f2bf(wt[(((size_t)c * 3 + kh) * 3 + kw) * O_ + o]);
}

// ---------------- Pass 1: fused implicit-GEMM conv, COALESCED in-block transpose ----
// Per block: 5 input h-rows are read coalesced (f32x4) into a f32 scratch tile,
// then transposed in-LDS into the XOR-swizzled bf16 A-union layout. No xpad
// intermediate, no scattered loads (R8's failure). MFMA core identical to R4.
__global__ __launch_bounds__(256, 2) void conv_gemm(
    const float* __restrict__ x,
    const char* __restrict__ wbuf,
    float* __restrict__ out)
{
    __shared__ float scratch[64][114];   // 29184 B; stride 114: b64-aligned, bank-clean
    __shared__ char ldsA[NROWS * 128];   // 46336 B; total 75520 -> 2 blocks/CU

    const int t = threadIdx.x;
    const int lane = t & 63, wid = t >> 6;
    const int wr = wid >> 1, wc = wid & 1;
    const int bid0 = blockIdx.x;
    const int bid = (bid0 & 7) * 196 + (bid0 >> 3);  // XCD swizzle, 1568 = 8*196 exact
    const int b = bid / 98;                 // 98 M-tiles per batch, exact
    const int ml0 = (bid % 98) * 128;
    const int oh0 = ml0 / W_;
    const int pbase = ml0 + 2 * oh0;        // first padded-plane row of the union

    const float* xb = x + (size_t)b * C_ * HW;

    // ---- Staging: 5 padded h-rows ph = oh0..oh0+4 cover the 362-row union.
    for (int d = 0; d < 5; ++d) {
        const int ph = oh0 + d;
        const int ih = ph - 1;                       // input row
        const bool rowvalid = (ih >= 0 && ih < H_);
        if (rowvalid) {
            const float* xr = xb + (size_t)ih * W_;
            #pragma unroll
            for (int k = 0; k < 7; ++k) {            // 64c * 28 x4-chunks = 1792
                int flat = k * 256 + t;
                int c = flat / 28, w4 = flat % 28;
                f32x4 v = *(const f32x4*)(xr + (size_t)c * HW + w4 * 4);
                *(float2*)&scratch[c][w4 * 4]     = make_float2(v.x, v.y);
                *(float2*)&scratch[c][w4 * 4 + 2] = make_float2(v.z, v.w);
            }
        }
        __syncthreads();
        // transpose-write this padded row's units: u = pw*8 + pos, 912 units
        #pragma unroll
        for (int k = 0; k < 4; ++k) {
            int u = k * 256 + t;
            if (u < 912) {
                const int pw = u >> 3, pos = u & 7;
                const int r = ph * HP + pw - pbase;
                if (r >= 0 && r < NROWS) {
                    union { uint32_t w[4]; short8 s; } v;
                    v.w[0] = v.w[1] = v.w[2] = v.w[3] = 0;
                    if (rowvalid && pw >= 1 && pw <= 112) {
                        const int c0 = (pos ^ (r & 7)) << 3;
                        float f0 = scratch[c0 + 0][pw - 1];
                        float f1 = scratch[c0 + 1][pw - 1];
                        float f2 = scratch[c0 + 2][pw - 1];
                        float f3 = scratch[c0 + 3][pw - 1];
                        float f4 = scratch[c0 + 4][pw - 1];
                        float f5 = scratch[c0 + 5][pw - 1];
                        float f6 = scratch[c0 + 6][pw - 1];
                        float f7 = scratch[c0 + 7][pw - 1];
                        asm("v_cvt_pk_bf16_f32 %0, %1, %2" : "=v"(v.w[0]) : "v"(f0), "v"(f1));
                        asm("v_cvt_pk_bf16_f32 %0, %1, %2" : "=v"(v.w[1]) : "v"(f2), "v"(f3));
                        asm("v_cvt_pk_bf16_f32 %0, %1, %2" : "=v"(v.w[2]) : "v"(f4), "v"(f5));
                        asm("v_cvt_pk_bf16_f32 %0, %1, %2" : "=v"(v.w[3]) : "v"(f6), "v"(f7));
                    }
                    *(short8*)(ldsA + (size_t)r * 128 + (pos << 4)) = v.s;
                }
            }
        }
        __syncthreads();   // scratch reusable / A-writes visible
    }

    // Per-fragment LDS base rows (per-lane): row = ml + 2*oh - pbase
    int rowb[4];
    #pragma unroll
    for (int mf = 0; mf < 4; ++mf) {
        int ml = ml0 + wr * 64 + mf * 16 + (lane & 15);
        int oh = ml / W_;
        rowb[mf] = ml + 2 * oh - pbase;
    }
    const int kq = lane >> 4;   // k-quarter 0..3

    f32x4 acc[4][4] = {};

    #pragma unroll
    for (int s = 0; s < 9; ++s) {
        const int soff = (s / 3) * HP + (s % 3);
        const char* wb = wbuf + s * 16384 + wc * 4096 + lane * 16;

        #pragma unroll
        for (int ks = 0; ks < 2; ++ks) {
            // B fragments: 4 coalesced 1KB loads per wave from L2-resident wbuf
            short8 bv[4];
            #pragma unroll
            for (int nf = 0; nf < 4; ++nf)
                bv[nf] = *(const short8*)(wb + ks * 8192 + nf * 1024);

            short8 av[4];
            #pragma unroll
            for (int mf = 0; mf < 4; ++mf) {
                const int lrow = rowb[mf] + soff;
                const int ck = (ks * 4 + kq) ^ (lrow & 7);
                av[mf] = *(const short8*)(ldsA + lrow * 128 + (ck << 4));
            }
            __builtin_amdgcn_s_setprio(1);
            #pragma unroll
            for (int mf = 0; mf < 4; ++mf)
                #pragma unroll
                for (int nf = 0; nf < 4; ++nf)
                    acc[mf][nf] = __builtin_amdgcn_mfma_f32_16x16x32_bf16(
                        av[mf], bv[nf], acc[mf][nf], 0, 0, 0);
            __builtin_amdgcn_s_setprio(0);
        }
    }

    // Epilogue: C/D layout col=lane&15 (o), row=(lane>>4)*4+reg (m).
    const int oc = wc * 64 + (lane & 15);
    const int mrow = ml0 + wr * 64 + ((lane >> 4) << 2);
    #pragma unroll
    for (int mf = 0; mf < 4; ++mf) {
        #pragma unroll
        for (int nf = 0; nf < 4; ++nf) {
            float* dst = out + ((size_t)(b * O_ + oc + nf * 16) * HW) + mrow + mf * 16;
            *(f32x4*)dst = acc[mf][nf];
        }
    }
}

extern "C" void kernel_launch(void* const* d_in, const int* in_sizes, int n_in,
                              void* d_out, int out_size, void* d_ws, size_t ws_size,
                              hipStream_t stream) {
    const float* x  = (const float*)d_in[0];
    const float* wt = (const float*)d_in[1];
    float* out = (float*)d_out;
    char* wbuf = (char*)d_ws;

    hipLaunchKernelGGL(wtrans, dim3(288), dim3(256), 0, stream,
                       wt, (unsigned short*)wbuf);
    hipLaunchKernelGGL(conv_gemm, dim3(1568), dim3(256), 0, stream,
                       x, wbuf, out);
}